// Round 4
// baseline (160.211 us; speedup 1.0000x reference)
//
#include <hip/hip_runtime.h>

// ---- problem constants ----
constexpr int  Bn    = 512;
constexpr int  Dd    = 128;
constexpr int  QUEUE = 65536;
constexpr int  NEGR  = 8192;              // B*N in-batch negatives
constexpr int  NJ    = NEGR + QUEUE;      // 73728 negative columns
constexpr long long OUTC    = 1 + NJ;     // 73729 out row stride
constexpr long long MEM_OFF = 2LL * Bn * OUTC;  // new_memory offset in d_out

constexpr int NBLK = 256;                 // exactly 1 block per CU
constexpr int CPB  = 288;                 // columns per block (18 groups of 16)

typedef __attribute__((ext_vector_type(8))) short  short8;
typedef __attribute__((ext_vector_type(4))) float  floatx4;

__device__ __forceinline__ unsigned short f2bf(float f) {
    union { float f; unsigned u; } x; x.f = f;
    unsigned u = x.u;
    u += 0x7fffu + ((u >> 16) & 1u);   // round-to-nearest-even
    return (unsigned short)(u >> 16);
}

__device__ __forceinline__ short8 pack8(float4 a, float4 b) {
    short8 r;
    r[0] = (short)f2bf(a.x); r[1] = (short)f2bf(a.y);
    r[2] = (short)f2bf(a.z); r[3] = (short)f2bf(a.w);
    r[4] = (short)f2bf(b.x); r[5] = (short)f2bf(b.y);
    r[6] = (short)f2bf(b.z); r[7] = (short)f2bf(b.w);
    return r;
}

// ---- kernel 0: q (512x128 f32) -> bf16 in workspace ----
__global__ void qconv(const float* __restrict__ q, unsigned short* __restrict__ qb) {
    int t = blockIdx.x * blockDim.x + threadIdx.x;      // 16384 threads, 4 elems each
    float4 v = *(const float4*)(q + (long long)t * 4);
    ushort4 r;
    r.x = f2bf(v.x); r.y = f2bf(v.y); r.z = f2bf(v.z); r.w = f2bf(v.w);
    *(ushort4*)(qb + (long long)t * 4) = r;
}

// ---- fused, uniform-work kernel: 256 blocks x 512 threads (8 waves) ----
// Each block: 288 gemm columns (wave w -> groups {w, w+8}; waves 0,1 also group 16+w),
// 2 positive-logit rows (waves 6,7), 256 memory-queue rows (all threads).
__global__ __launch_bounds__(512) void fused(const unsigned short* __restrict__ qb,
                                             const float* __restrict__ negs,
                                             const float* __restrict__ mem,
                                             const float* __restrict__ q,
                                             const float* __restrict__ k,
                                             const float* __restrict__ ps,
                                             const float* __restrict__ k_all,
                                             const int* __restrict__ indexp,
                                             float* __restrict__ out) {
    const int tid  = threadIdx.x;
    const int lane = tid & 63;
    const int wave = tid >> 6;            // 0..7
    const int l16  = lane & 15;
    const int kg   = lane >> 4;           // 0..3
    const int klo  = kg * 8;
    const int b    = blockIdx.x;
    // XCD swizzle: 256 = 8 * 32, adjacent column stripes on the same XCD's L2
    const int stripe = (b & 7) * 32 + (b >> 3);
    const long long jb = (long long)stripe * CPB;

    // ---- gemm pass A: 2 persistent B-frag groups per wave ----
    short8 bfA[2][4];
    #pragma unroll
    for (int i = 0; i < 2; ++i) {
        const long long jrow = jb + (wave + i * 8) * 16 + l16;
        const float* src = (jrow < NEGR) ? (negs + jrow * Dd)
                                         : (mem + (jrow - NEGR) * Dd);
        #pragma unroll
        for (int s = 0; s < 4; ++s) {
            float4 x = *(const float4*)(src + s * 32 + klo);
            float4 y = *(const float4*)(src + s * 32 + klo + 4);
            bfA[i][s] = pack8(x, y);
        }
    }
    #pragma unroll 1
    for (int m = 0; m < 32; ++m) {
        const unsigned short* arow = qb + (long long)(m * 16 + l16) * Dd + klo;
        short8 af[4];
        #pragma unroll
        for (int s = 0; s < 4; ++s) af[s] = *(const short8*)(arow + s * 32);
        const int row0 = m * 16 + kg * 4;     // C/D: row = (lane>>4)*4 + reg
        #pragma unroll
        for (int i = 0; i < 2; ++i) {
            floatx4 acc = {0.f, 0.f, 0.f, 0.f};
            #pragma unroll
            for (int s = 0; s < 4; ++s)
                acc = __builtin_amdgcn_mfma_f32_16x16x32_bf16(af[s], bfA[i][s], acc, 0, 0, 0);
            float* o0 = out + (long long)row0 * OUTC + 1 + jb + (wave + i * 8) * 16 + l16;
            #pragma unroll
            for (int r = 0; r < 4; ++r) {
                float v = acc[r] * 10.0f;
                o0[(long long)r * OUTC]        = v;
                o0[((long long)r + Bn) * OUTC] = v;
            }
        }
    }
    // ---- gemm pass B: waves 0,1 take groups 16,17 (static code path, rule #20) ----
    if (wave < 2) {
        short8 bfB[4];
        const long long jrow = jb + (16 + wave) * 16 + l16;
        const float* src = (jrow < NEGR) ? (negs + jrow * Dd)
                                         : (mem + (jrow - NEGR) * Dd);
        #pragma unroll
        for (int s = 0; s < 4; ++s) {
            float4 x = *(const float4*)(src + s * 32 + klo);
            float4 y = *(const float4*)(src + s * 32 + klo + 4);
            bfB[s] = pack8(x, y);
        }
        #pragma unroll 1
        for (int m = 0; m < 32; ++m) {
            const unsigned short* arow = qb + (long long)(m * 16 + l16) * Dd + klo;
            short8 af[4];
            #pragma unroll
            for (int s = 0; s < 4; ++s) af[s] = *(const short8*)(arow + s * 32);
            floatx4 acc = {0.f, 0.f, 0.f, 0.f};
            #pragma unroll
            for (int s = 0; s < 4; ++s)
                acc = __builtin_amdgcn_mfma_f32_16x16x32_bf16(af[s], bfB[s], acc, 0, 0, 0);
            const int row0 = m * 16 + kg * 4;
            float* o0 = out + (long long)row0 * OUTC + 1 + jb + (16 + wave) * 16 + l16;
            #pragma unroll
            for (int r = 0; r < 4; ++r) {
                float v = acc[r] * 10.0f;
                o0[(long long)r * OUTC]        = v;
                o0[((long long)r + Bn) * OUTC] = v;
            }
        }
    }
    // ---- positive logits: waves 6,7 -> rows 2b, 2b+1 ----
    if (wave >= 6) {
        const int br = b * 2 + (wave - 6);
        float2 qv = *(const float2*)(q + (long long)br * Dd + lane * 2);
        float2 kv = *(const float2*)(k + (long long)br * Dd + lane * 2);
        float pk = qv.x * kv.x + qv.y * kv.y;
        float pp = 0.f;
        #pragma unroll
        for (int p = 0; p < 4; ++p) {
            float2 pv = *(const float2*)(ps + ((long long)br * 4 + p) * Dd + lane * 2);
            pp += qv.x * pv.x + qv.y * pv.y;
        }
        #pragma unroll
        for (int off = 32; off; off >>= 1) {
            pk += __shfl_xor(pk, off);
            pp += __shfl_xor(pp, off);
        }
        if (lane == 0) {
            out[(long long)br * OUTC]        = pk * 10.0f;
            out[((long long)br + Bn) * OUTC] = (pp * 0.25f) * 10.0f;
        }
    }
    // ---- new_memory: rows b*256 .. b*256+255 (128 KB per block, uniform) ----
    {
        float* outmem = out + MEM_OFF;
        const int index = *indexp;
        #pragma unroll 1
        for (int it = 0; it < 16; ++it) {
            int idx = it * 512 + tid;               // 8192 float4 chunks per block
            int row = b * 256 + (idx >> 5);
            int c4  = idx & 31;
            int src = (row - index) & (QUEUE - 1);
            float4 v;
            if (src < Bn) v = *(const float4*)(k_all + (long long)src * Dd + c4 * 4);
            else          v = *(const float4*)(mem   + (long long)row * Dd + c4 * 4);
            *(float4*)(outmem + (long long)row * Dd + c4 * 4) = v;
        }
    }
}

extern "C" void kernel_launch(void* const* d_in, const int* in_sizes, int n_in,
                              void* d_out, int out_size, void* d_ws, size_t ws_size,
                              hipStream_t stream) {
    const float* q      = (const float*)d_in[0];
    const float* k      = (const float*)d_in[1];
    const float* pos    = (const float*)d_in[2];
    const float* negs   = (const float*)d_in[3];
    const float* k_all  = (const float*)d_in[4];
    const float* memory = (const float*)d_in[5];
    const int*   indexp = (const int*)d_in[6];
    float* out = (float*)d_out;
    unsigned short* qb = (unsigned short*)d_ws;   // 512*128*2 = 128 KB

    qconv<<<64, 256, 0, stream>>>(q, qb);
    fused<<<NBLK, 512, 0, stream>>>(qb, negs, memory, q, k, pos, k_all, indexp, out);
}

// Round 5
// 118.474 us; speedup vs baseline: 1.3523x; 1.3523x over previous
//
#include <hip/hip_runtime.h>

// ---- problem constants ----
constexpr int  Bn    = 512;
constexpr int  Dd    = 128;
constexpr int  QUEUE = 65536;
constexpr int  NEGR  = 8192;              // B*N in-batch negatives
constexpr int  NJ    = NEGR + QUEUE;      // 73728 negative columns
constexpr long long OUTC    = 1 + NJ;     // 73729 out row stride
constexpr long long MEM_OFF = 2LL * Bn * OUTC;  // new_memory offset in d_out

// fused-kernel block ranges
// gemm: 288 column-stripes (256 cols) x 4 m-quarters = 1152 blocks.
// Finer quantum fixes the R3 tail (32 CUs did 2x work); inner store pattern
// (4 waves x 64-col contiguous stripes, back-to-back 256B store runs) is
// UNCHANGED from the proven 104us R3 kernel. B re-read x4 is L3-served.
constexpr int GEMM_BLK = 1152;
constexpr int POS_BLK  = Bn / 4;          // 128 blocks, 4 rows each (4 waves)
constexpr int MEM_BLK  = 256;             // grid-stride memory-copy blocks
constexpr int TOT_BLK  = GEMM_BLK + POS_BLK + MEM_BLK;

typedef __attribute__((ext_vector_type(8))) short  short8;
typedef __attribute__((ext_vector_type(4))) float  floatx4;

__device__ __forceinline__ unsigned short f2bf(float f) {
    union { float f; unsigned u; } x; x.f = f;
    unsigned u = x.u;
    u += 0x7fffu + ((u >> 16) & 1u);   // round-to-nearest-even
    return (unsigned short)(u >> 16);
}

__device__ __forceinline__ short8 pack8(float4 a, float4 b) {
    short8 r;
    r[0] = (short)f2bf(a.x); r[1] = (short)f2bf(a.y);
    r[2] = (short)f2bf(a.z); r[3] = (short)f2bf(a.w);
    r[4] = (short)f2bf(b.x); r[5] = (short)f2bf(b.y);
    r[6] = (short)f2bf(b.z); r[7] = (short)f2bf(b.w);
    return r;
}

// ---- kernel 0: q (512x128 f32) -> bf16 in workspace ----
__global__ void qconv(const float* __restrict__ q, unsigned short* __restrict__ qb) {
    int t = blockIdx.x * blockDim.x + threadIdx.x;      // 16384 threads, 4 elems each
    float4 v = *(const float4*)(q + (long long)t * 4);
    ushort4 r;
    r.x = f2bf(v.x); r.y = f2bf(v.y); r.z = f2bf(v.z); r.w = f2bf(v.w);
    *(ushort4*)(qb + (long long)t * 4) = r;
}

// ---- fused kernel: [0,1152) gemm | [1152,1280) positive col | [1280,1536) memory copy ----
__global__ __launch_bounds__(256) void fused(const unsigned short* __restrict__ qb,
                                             const float* __restrict__ negs,
                                             const float* __restrict__ mem,
                                             const float* __restrict__ q,
                                             const float* __restrict__ k,
                                             const float* __restrict__ ps,
                                             const float* __restrict__ k_all,
                                             const int* __restrict__ indexp,
                                             float* __restrict__ out) {
    const int blk  = blockIdx.x;
    const int lane = threadIdx.x & 63;
    const int wave = threadIdx.x >> 6;

    if (blk < GEMM_BLK) {
        // ---- GEMM: 256 cols/block, 64 cols/wave (4 adjacent j-groups), 8 m-tiles ----
        const int l16 = lane & 15;
        const int kg  = lane >> 4;        // 0..3
        const int klo = kg * 8;
        // XCD swizzle: 1152 = 8*144. t walks (m-quarter, then stripe) along a
        // same-XCD block chain (b, b+8, ...), so stripes s and s+1 — which share
        // the partial 128B lines at their column edge — land on the same XCD L2,
        // and all 4 m-quarters of a stripe do too.
        const int t  = (blk & 7) * 144 + (blk >> 3);
        const int s  = t >> 2;            // column stripe 0..287
        const int mq = t & 3;             // m-quarter 0..3
        const long long jbase = (long long)s * 256 + wave * 64;

        // B fragments: 4 adjacent j-groups x 4 k-slices; converted f32->bf16 in regs
        short8 bfrag[4][4];
        #pragma unroll
        for (int g = 0; g < 4; ++g) {
            const long long jrow = jbase + g * 16 + l16;
            const float* src = (jrow < NEGR) ? (negs + jrow * Dd)
                                             : (mem + (jrow - NEGR) * Dd);
            #pragma unroll
            for (int sl = 0; sl < 4; ++sl) {
                float4 x = *(const float4*)(src + sl * 32 + klo);
                float4 y = *(const float4*)(src + sl * 32 + klo + 4);
                bfrag[g][sl] = pack8(x, y);
            }
        }

        const int m0 = mq * 8;
        #pragma unroll 1
        for (int m = m0; m < m0 + 8; ++m) {
            const unsigned short* arow = qb + (long long)(m * 16 + l16) * Dd + klo;
            short8 af[4];
            #pragma unroll
            for (int sl = 0; sl < 4; ++sl) af[sl] = *(const short8*)(arow + sl * 32);
            const int row0 = m * 16 + kg * 4;     // C/D: row = (lane>>4)*4 + reg
            float* o0 = out + (long long)row0 * OUTC + 1 + jbase + l16;
            #pragma unroll
            for (int g = 0; g < 4; ++g) {
                floatx4 acc = {0.f, 0.f, 0.f, 0.f};
                #pragma unroll
                for (int sl = 0; sl < 4; ++sl)
                    acc = __builtin_amdgcn_mfma_f32_16x16x32_bf16(af[sl], bfrag[g][sl], acc, 0, 0, 0);
                #pragma unroll
                for (int r = 0; r < 4; ++r) {
                    float v = acc[r] * 10.0f;
                    o0[(long long)r * OUTC + g * 16]            = v;
                    o0[((long long)r + Bn) * OUTC + g * 16]     = v;
                }
            }
        }
    } else if (blk < GEMM_BLK + POS_BLK) {
        // ---- positive logits -> out column 0 (one wave per batch row) ----
        const int b = (blk - GEMM_BLK) * 4 + wave;
        float2 qv = *(const float2*)(q + (long long)b * Dd + lane * 2);
        float2 kv = *(const float2*)(k + (long long)b * Dd + lane * 2);
        float pk = qv.x * kv.x + qv.y * kv.y;
        float pp = 0.f;
        #pragma unroll
        for (int p = 0; p < 4; ++p) {
            float2 pv = *(const float2*)(ps + ((long long)b * 4 + p) * Dd + lane * 2);
            pp += qv.x * pv.x + qv.y * pv.y;
        }
        #pragma unroll
        for (int off = 32; off; off >>= 1) {
            pk += __shfl_xor(pk, off);
            pp += __shfl_xor(pp, off);
        }
        if (lane == 0) {
            out[(long long)b * OUTC]        = pk * 10.0f;
            out[((long long)b + Bn) * OUTC] = (pp * 0.25f) * 10.0f;
        }
    } else {
        // ---- new_memory = memory with rows (i+index)%Q <- k_all[i] ----
        float* outmem = out + MEM_OFF;
        const int index = *indexp;
        const long long total = (long long)QUEUE * (Dd / 4);   // float4 chunks
        const long long stride = (long long)MEM_BLK * 256;
        for (long long i = (long long)(blk - GEMM_BLK - POS_BLK) * 256 + threadIdx.x;
             i < total; i += stride) {
            int row = (int)(i >> 5);          // D/4 = 32 chunks per row
            int c4  = (int)(i & 31);
            int src = (row - index) & (QUEUE - 1);
            float4 v;
            if (src < Bn) v = *(const float4*)(k_all + (long long)src * Dd + c4 * 4);
            else          v = *(const float4*)(mem   + (long long)row * Dd + c4 * 4);
            *(float4*)(outmem + (long long)row * Dd + c4 * 4) = v;
        }
    }
}

extern "C" void kernel_launch(void* const* d_in, const int* in_sizes, int n_in,
                              void* d_out, int out_size, void* d_ws, size_t ws_size,
                              hipStream_t stream) {
    const float* q      = (const float*)d_in[0];
    const float* k      = (const float*)d_in[1];
    const float* pos    = (const float*)d_in[2];
    const float* negs   = (const float*)d_in[3];
    const float* k_all  = (const float*)d_in[4];
    const float* memory = (const float*)d_in[5];
    const int*   indexp = (const int*)d_in[6];
    float* out = (float*)d_out;
    unsigned short* qb = (unsigned short*)d_ws;   // 512*128*2 = 128 KB

    qconv<<<64, 256, 0, stream>>>(q, qb);
    fused<<<TOT_BLK, 256, 0, stream>>>(qb, negs, memory, q, k, pos, k_all, indexp, out);
}

// Round 6
// 88.737 us; speedup vs baseline: 1.8055x; 1.3351x over previous
//
#include <hip/hip_runtime.h>

// ---- problem constants ----
constexpr int  Bn    = 512;
constexpr int  Dd    = 128;
constexpr int  QUEUE = 65536;
constexpr int  NEGR  = 8192;              // B*N in-batch negatives
constexpr int  NJ    = NEGR + QUEUE;      // 73728 negative columns
constexpr long long OUTC    = 1 + NJ;     // 73729 out row stride
constexpr long long MEM_OFF = 2LL * Bn * OUTC;  // new_memory offset in d_out

// fused-kernel block ranges (EXACT R3 grid — only the store path changed)
constexpr int GEMM_BLK = NJ / 256;        // 288 blocks, 256 cols each
constexpr int POS_BLK  = Bn / 4;          // 128 blocks, 4 rows each (4 waves)
constexpr int MEM_BLK  = 256;             // grid-stride memory-copy blocks
constexpr int TOT_BLK  = GEMM_BLK + POS_BLK + MEM_BLK;

constexpr int LDS_STRIDE = 260;           // 16-row x 256-col f32 tile, pad 260:
                                          // all ds accesses <=2-way (free, m136)

typedef __attribute__((ext_vector_type(8))) short  short8;
typedef __attribute__((ext_vector_type(4))) float  floatx4;

__device__ __forceinline__ unsigned short f2bf(float f) {
    union { float f; unsigned u; } x; x.f = f;
    unsigned u = x.u;
    u += 0x7fffu + ((u >> 16) & 1u);   // round-to-nearest-even
    return (unsigned short)(u >> 16);
}

__device__ __forceinline__ short8 pack8(float4 a, float4 b) {
    short8 r;
    r[0] = (short)f2bf(a.x); r[1] = (short)f2bf(a.y);
    r[2] = (short)f2bf(a.z); r[3] = (short)f2bf(a.w);
    r[4] = (short)f2bf(b.x); r[5] = (short)f2bf(b.y);
    r[6] = (short)f2bf(b.z); r[7] = (short)f2bf(b.w);
    return r;
}

// ---- kernel 0: q (512x128 f32) -> bf16 in workspace ----
__global__ void qconv(const float* __restrict__ q, unsigned short* __restrict__ qb) {
    int t = blockIdx.x * blockDim.x + threadIdx.x;      // 16384 threads, 4 elems each
    float4 v = *(const float4*)(q + (long long)t * 4);
    ushort4 r;
    r.x = f2bf(v.x); r.y = f2bf(v.y); r.z = f2bf(v.z); r.w = f2bf(v.w);
    *(ushort4*)(qb + (long long)t * 4) = r;
}

// ---- fused kernel: [0,288) gemm | [288,416) positive col | [416,672) memory copy ----
__global__ __launch_bounds__(256) void fused(const unsigned short* __restrict__ qb,
                                             const float* __restrict__ negs,
                                             const float* __restrict__ mem,
                                             const float* __restrict__ q,
                                             const float* __restrict__ k,
                                             const float* __restrict__ ps,
                                             const float* __restrict__ k_all,
                                             const int* __restrict__ indexp,
                                             float* __restrict__ out) {
    __shared__ float tile[16 * LDS_STRIDE];   // 16.6 KB, only used by gemm blocks

    const int blk  = blockIdx.x;
    const int lane = threadIdx.x & 63;
    const int wave = threadIdx.x >> 6;

    if (blk < GEMM_BLK) {
        // ---- GEMM: 256 cols/block, 64 cols/wave (4 j-groups of 16) ----
        const int l16 = lane & 15;
        const int kg  = lane >> 4;        // 0..3
        const int klo = kg * 8;
        // XCD swizzle: 288 = 8 * 36 -> adjacent stripes on same XCD's L2
        const int stripe = (blk & 7) * 36 + (blk >> 3);
        const long long jbase0 = (long long)stripe * 256;          // block col base
        const long long jbase  = jbase0 + wave * 64;               // wave col base

        // B fragments: 4 j-groups x 4 k-slices; converted f32->bf16 in regs
        short8 bfrag[4][4];
        #pragma unroll
        for (int g = 0; g < 4; ++g) {
            const long long jrow = jbase + g * 16 + l16;
            const float* src = (jrow < NEGR) ? (negs + jrow * Dd)
                                             : (mem + (jrow - NEGR) * Dd);
            #pragma unroll
            for (int s = 0; s < 4; ++s) {
                float4 x = *(const float4*)(src + s * 32 + klo);
                float4 y = *(const float4*)(src + s * 32 + klo + 4);
                bfrag[g][s] = pack8(x, y);
            }
        }

        #pragma unroll 1
        for (int m = 0; m < 32; ++m) {
            const unsigned short* arow = qb + (long long)(m * 16 + l16) * Dd + klo;
            short8 af[4];
            #pragma unroll
            for (int s = 0; s < 4; ++s) af[s] = *(const short8*)(arow + s * 32);
            // compute 16 values/thread, scale, stage into LDS (transpose via LDS:
            // MFMA layout scatters a wave over 4 rows -> 64B misaligned segments;
            // staged stores below are 256B wave-contiguous instead)
            #pragma unroll
            for (int g = 0; g < 4; ++g) {
                floatx4 acc = {0.f, 0.f, 0.f, 0.f};
                #pragma unroll
                for (int s = 0; s < 4; ++s)
                    acc = __builtin_amdgcn_mfma_f32_16x16x32_bf16(af[s], bfrag[g][s], acc, 0, 0, 0);
                const int tcol = wave * 64 + g * 16 + l16;
                #pragma unroll
                for (int r = 0; r < 4; ++r)
                    tile[(kg * 4 + r) * LDS_STRIDE + tcol] = acc[r] * 10.0f;
            }
            __syncthreads();
            // cooperative write-out: wave w -> tile rows {w, w+4, w+8, w+12};
            // per row 4 passes of 64 lanes x 4B = 256B contiguous per instruction
            #pragma unroll
            for (int i = 0; i < 16; ++i) {
                const int trow = (i >> 2) * 4 + wave;
                const int p    = i & 3;
                const float v  = tile[trow * LDS_STRIDE + p * 64 + lane];
                const long long grow = (long long)(m * 16 + trow);
                const long long gcol = 1 + jbase0 + p * 64 + lane;
                out[grow * OUTC + gcol]        = v;
                out[(grow + Bn) * OUTC + gcol] = v;
            }
            __syncthreads();
        }
    } else if (blk < GEMM_BLK + POS_BLK) {
        // ---- positive logits -> out column 0 (one wave per batch row) ----
        const int b = (blk - GEMM_BLK) * 4 + wave;
        float2 qv = *(const float2*)(q + (long long)b * Dd + lane * 2);
        float2 kv = *(const float2*)(k + (long long)b * Dd + lane * 2);
        float pk = qv.x * kv.x + qv.y * kv.y;
        float pp = 0.f;
        #pragma unroll
        for (int p = 0; p < 4; ++p) {
            float2 pv = *(const float2*)(ps + ((long long)b * 4 + p) * Dd + lane * 2);
            pp += qv.x * pv.x + qv.y * pv.y;
        }
        #pragma unroll
        for (int off = 32; off; off >>= 1) {
            pk += __shfl_xor(pk, off);
            pp += __shfl_xor(pp, off);
        }
        if (lane == 0) {
            out[(long long)b * OUTC]        = pk * 10.0f;
            out[((long long)b + Bn) * OUTC] = (pp * 0.25f) * 10.0f;
        }
    } else {
        // ---- new_memory = memory with rows (i+index)%Q <- k_all[i] ----
        float* outmem = out + MEM_OFF;
        const int index = *indexp;
        const long long total = (long long)QUEUE * (Dd / 4);   // float4 chunks
        const long long stride = (long long)MEM_BLK * 256;
        for (long long i = (long long)(blk - GEMM_BLK - POS_BLK) * 256 + threadIdx.x;
             i < total; i += stride) {
            int row = (int)(i >> 5);          // D/4 = 32 chunks per row
            int c4  = (int)(i & 31);
            int src = (row - index) & (QUEUE - 1);
            float4 v;
            if (src < Bn) v = *(const float4*)(k_all + (long long)src * Dd + c4 * 4);
            else          v = *(const float4*)(mem   + (long long)row * Dd + c4 * 4);
            *(float4*)(outmem + (long long)row * Dd + c4 * 4) = v;
        }
    }
}

extern "C" void kernel_launch(void* const* d_in, const int* in_sizes, int n_in,
                              void* d_out, int out_size, void* d_ws, size_t ws_size,
                              hipStream_t stream) {
    const float* q      = (const float*)d_in[0];
    const float* k      = (const float*)d_in[1];
    const float* pos    = (const float*)d_in[2];
    const float* negs   = (const float*)d_in[3];
    const float* k_all  = (const float*)d_in[4];
    const float* memory = (const float*)d_in[5];
    const int*   indexp = (const int*)d_in[6];
    float* out = (float*)d_out;
    unsigned short* qb = (unsigned short*)d_ws;   // 512*128*2 = 128 KB

    qconv<<<64, 256, 0, stream>>>(q, qb);
    fused<<<TOT_BLK, 256, 0, stream>>>(qb, negs, memory, q, k, pos, k_all, indexp, out);
}

// Round 7
// 83.904 us; speedup vs baseline: 1.9095x; 1.0576x over previous
//
#include <hip/hip_runtime.h>

// ---- problem constants ----
constexpr int  Bn    = 512;
constexpr int  Dd    = 128;
constexpr int  QUEUE = 65536;
constexpr int  NEGR  = 8192;              // B*N in-batch negatives
constexpr int  NJ    = NEGR + QUEUE;      // 73728 negative columns
constexpr long long OUTC    = 1 + NJ;     // 73729 out row stride
constexpr long long MEM_OFF = 2LL * Bn * OUTC;  // new_memory offset in d_out

// fused-kernel block ranges (EXACT R6 grid — only the write-out width changed)
constexpr int GEMM_BLK = NJ / 256;        // 288 blocks, 256 cols each
constexpr int POS_BLK  = Bn / 4;          // 128 blocks, 4 rows each (4 waves)
constexpr int MEM_BLK  = 256;             // grid-stride memory-copy blocks
constexpr int TOT_BLK  = GEMM_BLK + POS_BLK + MEM_BLK;

constexpr int LDS_STRIDE = 260;           // 16x256 f32 tile; 260*4=1040B row pitch
                                          // (16B-aligned rows for ds_read_b128)

typedef __attribute__((ext_vector_type(8))) short  short8;
typedef __attribute__((ext_vector_type(4))) float  floatx4;

__device__ __forceinline__ unsigned short f2bf(float f) {
    union { float f; unsigned u; } x; x.f = f;
    unsigned u = x.u;
    u += 0x7fffu + ((u >> 16) & 1u);   // round-to-nearest-even
    return (unsigned short)(u >> 16);
}

__device__ __forceinline__ short8 pack8(float4 a, float4 b) {
    short8 r;
    r[0] = (short)f2bf(a.x); r[1] = (short)f2bf(a.y);
    r[2] = (short)f2bf(a.z); r[3] = (short)f2bf(a.w);
    r[4] = (short)f2bf(b.x); r[5] = (short)f2bf(b.y);
    r[6] = (short)f2bf(b.z); r[7] = (short)f2bf(b.w);
    return r;
}

// ---- kernel 0: q (512x128 f32) -> bf16 in workspace ----
__global__ void qconv(const float* __restrict__ q, unsigned short* __restrict__ qb) {
    int t = blockIdx.x * blockDim.x + threadIdx.x;      // 16384 threads, 4 elems each
    float4 v = *(const float4*)(q + (long long)t * 4);
    ushort4 r;
    r.x = f2bf(v.x); r.y = f2bf(v.y); r.z = f2bf(v.z); r.w = f2bf(v.w);
    *(ushort4*)(qb + (long long)t * 4) = r;
}

// ---- fused kernel: [0,288) gemm | [288,416) positive col | [416,672) memory copy ----
__global__ __launch_bounds__(256) void fused(const unsigned short* __restrict__ qb,
                                             const float* __restrict__ negs,
                                             const float* __restrict__ mem,
                                             const float* __restrict__ q,
                                             const float* __restrict__ k,
                                             const float* __restrict__ ps,
                                             const float* __restrict__ k_all,
                                             const int* __restrict__ indexp,
                                             float* __restrict__ out) {
    __shared__ float tile[16 * LDS_STRIDE];   // 16.6 KB, only used by gemm blocks

    const int blk  = blockIdx.x;
    const int lane = threadIdx.x & 63;
    const int wave = threadIdx.x >> 6;

    if (blk < GEMM_BLK) {
        // ---- GEMM: 256 cols/block, 64 cols/wave (4 j-groups of 16) ----
        const int l16 = lane & 15;
        const int kg  = lane >> 4;        // 0..3
        const int klo = kg * 8;
        // XCD swizzle: 288 = 8 * 36 -> adjacent stripes on same XCD's L2
        const int stripe = (blk & 7) * 36 + (blk >> 3);
        const long long jbase0 = (long long)stripe * 256;          // block col base
        const long long jbase  = jbase0 + wave * 64;               // wave col base

        // B fragments: 4 j-groups x 4 k-slices; converted f32->bf16 in regs
        short8 bfrag[4][4];
        #pragma unroll
        for (int g = 0; g < 4; ++g) {
            const long long jrow = jbase + g * 16 + l16;
            const float* src = (jrow < NEGR) ? (negs + jrow * Dd)
                                             : (mem + (jrow - NEGR) * Dd);
            #pragma unroll
            for (int s = 0; s < 4; ++s) {
                float4 x = *(const float4*)(src + s * 32 + klo);
                float4 y = *(const float4*)(src + s * 32 + klo + 4);
                bfrag[g][s] = pack8(x, y);
            }
        }

        #pragma unroll 1
        for (int m = 0; m < 32; ++m) {
            const unsigned short* arow = qb + (long long)(m * 16 + l16) * Dd + klo;
            short8 af[4];
            #pragma unroll
            for (int s = 0; s < 4; ++s) af[s] = *(const short8*)(arow + s * 32);
            // compute 16 values/thread, scale, stage into LDS (transpose via LDS:
            // MFMA layout scatters a wave over 4 rows -> misaligned 64B segments)
            #pragma unroll
            for (int g = 0; g < 4; ++g) {
                floatx4 acc = {0.f, 0.f, 0.f, 0.f};
                #pragma unroll
                for (int s = 0; s < 4; ++s)
                    acc = __builtin_amdgcn_mfma_f32_16x16x32_bf16(af[s], bfrag[g][s], acc, 0, 0, 0);
                const int tcol = wave * 64 + g * 16 + l16;
                #pragma unroll
                for (int r = 0; r < 4; ++r)
                    tile[(kg * 4 + r) * LDS_STRIDE + tcol] = acc[r] * 10.0f;
            }
            __syncthreads();
            // cooperative write-out, dwordx4: wave w -> tile rows {w, w+4, w+8, w+12};
            // ds_read_b128 (consecutive 16B/lane, conflict-free) then ONE
            // global_store_dwordx4 per lane covers the whole 1KB row run:
            // 9 L2 line-transactions per KB (vs 12 with dword stores).
            #pragma unroll
            for (int i = 0; i < 4; ++i) {
                const int trow = i * 4 + wave;
                const float4 v = *(const float4*)&tile[trow * LDS_STRIDE + lane * 4];
                const long long grow = (long long)(m * 16 + trow);
                float* dst = out + grow * OUTC + 1 + jbase0 + lane * 4;
                *(float4*)dst                 = v;   // dword-aligned dwordx4: OK on gfx950
                *(float4*)(dst + Bn * OUTC)   = v;
            }
            __syncthreads();
        }
    } else if (blk < GEMM_BLK + POS_BLK) {
        // ---- positive logits -> out column 0 (one wave per batch row) ----
        const int b = (blk - GEMM_BLK) * 4 + wave;
        float2 qv = *(const float2*)(q + (long long)b * Dd + lane * 2);
        float2 kv = *(const float2*)(k + (long long)b * Dd + lane * 2);
        float pk = qv.x * kv.x + qv.y * kv.y;
        float pp = 0.f;
        #pragma unroll
        for (int p = 0; p < 4; ++p) {
            float2 pv = *(const float2*)(ps + ((long long)b * 4 + p) * Dd + lane * 2);
            pp += qv.x * pv.x + qv.y * pv.y;
        }
        #pragma unroll
        for (int off = 32; off; off >>= 1) {
            pk += __shfl_xor(pk, off);
            pp += __shfl_xor(pp, off);
        }
        if (lane == 0) {
            out[(long long)b * OUTC]        = pk * 10.0f;
            out[((long long)b + Bn) * OUTC] = (pp * 0.25f) * 10.0f;
        }
    } else {
        // ---- new_memory = memory with rows (i+index)%Q <- k_all[i] ----
        float* outmem = out + MEM_OFF;
        const int index = *indexp;
        const long long total = (long long)QUEUE * (Dd / 4);   // float4 chunks
        const long long stride = (long long)MEM_BLK * 256;
        for (long long i = (long long)(blk - GEMM_BLK - POS_BLK) * 256 + threadIdx.x;
             i < total; i += stride) {
            int row = (int)(i >> 5);          // D/4 = 32 chunks per row
            int c4  = (int)(i & 31);
            int src = (row - index) & (QUEUE - 1);
            float4 v;
            if (src < Bn) v = *(const float4*)(k_all + (long long)src * Dd + c4 * 4);
            else          v = *(const float4*)(mem   + (long long)row * Dd + c4 * 4);
            *(float4*)(outmem + (long long)row * Dd + c4 * 4) = v;
        }
    }
}

extern "C" void kernel_launch(void* const* d_in, const int* in_sizes, int n_in,
                              void* d_out, int out_size, void* d_ws, size_t ws_size,
                              hipStream_t stream) {
    const float* q      = (const float*)d_in[0];
    const float* k      = (const float*)d_in[1];
    const float* pos    = (const float*)d_in[2];
    const float* negs   = (const float*)d_in[3];
    const float* k_all  = (const float*)d_in[4];
    const float* memory = (const float*)d_in[5];
    const int*   indexp = (const int*)d_in[6];
    float* out = (float*)d_out;
    unsigned short* qb = (unsigned short*)d_ws;   // 512*128*2 = 128 KB

    qconv<<<64, 256, 0, stream>>>(q, qb);
    fused<<<TOT_BLK, 256, 0, stream>>>(qb, negs, memory, q, k, pos, k_all, indexp, out);
}